// Round 1
// 1017.557 us; speedup vs baseline: 1.2383x; 1.2383x over previous
//
#include <hip/hip_runtime.h>

// Problem: B=32, T=4096, DEC=1024, ENC=1024, ATTN=512, K=10
// out = [context (32*1024) | align (32*4096)] fp32
//
// Pipeline:
//  prep: wv -> bf16 pre-tiled+swizzled for LDS, qb2 = q@WQ^T + bias + convb@WU^T, A0/1/2 = conv taps @ WU^T
//  gemm: score[b,t] = fc_w . tanh(value@WV^T + qb2 + 3-tap(la)); sig = sigmoid; bsum[b] += sig
//  align = sig / bsum ; context = sum_t align * value (row-contiguous streaming + atomics)

typedef __attribute__((ext_vector_type(8))) short bf8_t;
typedef __attribute__((ext_vector_type(4))) float f4_t;

__device__ inline unsigned short f2bf(float f) {
    union { float f; unsigned u; } v; v.f = f;
    unsigned u = v.u + 0x7fffu + ((v.u >> 16) & 1u);  // RNE
    return (unsigned short)(u >> 16);
}
__device__ inline unsigned pk2(float x, float y) {
    return (unsigned)f2bf(x) | ((unsigned)f2bf(y) << 16);
}

__device__ inline void gload16(const void* g, void* l) {
    __builtin_amdgcn_global_load_lds(
        (const __attribute__((address_space(1))) unsigned int*)g,
        (__attribute__((address_space(3))) unsigned int*)l, 16, 0, 0);
}

// WV [512][1024] fp32 -> bf16, tiled per K-step of 64 and XOR-swizzled to be the exact
// LDS image: tile kt holds elems e in [kt*64, kt*64+64); elem (a,e) at
// kt*32768 + a*64 + ((e&63) ^ ((a&7)<<3)).   (byte swizzle = (row&7)<<4, guide G4)
__global__ void k_wv2bf(const float* __restrict__ wv, unsigned short* __restrict__ out) {
    int i = blockIdx.x * 256 + threadIdx.x;   // 65536 threads, 8 elems each
    int a = i >> 7;                           // 0..511
    int e0 = (i & 127) << 3;                  // 0..1016
    const float4* src = (const float4*)(wv + (size_t)a * 1024 + e0);
    float4 v0 = src[0], v1 = src[1];
    uint4 p;
    p.x = pk2(v0.x, v0.y); p.y = pk2(v0.z, v0.w);
    p.z = pk2(v1.x, v1.y); p.w = pk2(v1.z, v1.w);
    int kt = e0 >> 6;
    int kx = (e0 & 63) ^ ((a & 7) << 3);
    *(uint4*)(out + (size_t)kt * 32768 + a * 64 + kx) = p;
}

__global__ void k_qb2(const float* __restrict__ query, const float* __restrict__ WQ,
                      const float* __restrict__ bias, const float* __restrict__ convb,
                      const float* __restrict__ WU, float* __restrict__ qb2) {
    __shared__ float qs[1024];
    int b = blockIdx.x;
    for (int d = threadIdx.x; d < 1024; d += 256) qs[d] = query[b * 1024 + d];
    __syncthreads();
    for (int a = threadIdx.x; a < 512; a += 256) {
        float s = bias[a];
        for (int k = 0; k < 10; k++) s += convb[k] * WU[a * 10 + k];
        const float4* wq = (const float4*)(WQ + a * 1024);
        const float4* q4 = (const float4*)qs;
        float acc = 0.f;
        for (int d = 0; d < 256; d++) {
            float4 w = wq[d]; float4 q = q4[d];
            acc += w.x * q.x + w.y * q.y + w.z * q.z + w.w * q.w;
        }
        qb2[b * 512 + a] = s + acc;
    }
}

__global__ void k_a012(const float* __restrict__ cw, const float* __restrict__ WU,
                       float* __restrict__ a012) {
    int a = blockIdx.x * 256 + threadIdx.x;
    if (a < 512) {
        float s0 = 0.f, s1 = 0.f, s2 = 0.f;
        for (int k = 0; k < 10; k++) {
            float w = WU[a * 10 + k];
            s0 += cw[k * 3 + 0] * w;
            s1 += cw[k * 3 + 1] * w;
            s2 += cw[k * 3 + 2] * w;
        }
        a012[a] = s0; a012[512 + a] = s1; a012[1024 + a] = s2;
    }
}

// GEMM: 1024 blocks x 512 threads. Block tile 128x512, BK=64, 16 K-steps.
// B: double-buffered LDS via global_load_lds from pre-swizzled wvbf (counted vmcnt).
// A: fp32->bf16 reg-staged 1 step ahead, single LDS buffer, write-late after barrier.
__global__ __launch_bounds__(512, 2) void k_gemm(
    const float* __restrict__ value, const unsigned short* __restrict__ wvbf,
    const float* __restrict__ qb2, const float* __restrict__ a012,
    const float* __restrict__ fcw, const float* __restrict__ la,
    float* __restrict__ sigbuf, float* __restrict__ bsum) {
    __shared__ unsigned short Bs[2][512 * 64];   // 128 KB, swizzled image copied linearly
    __shared__ unsigned short As[128 * 64];      // 16 KB, swizzled
    __shared__ float rowLa[3][128];
    __shared__ float scoreRed[128][4];

    const int tid = threadIdx.x;
    const int lane = tid & 63;
    const int wave = tid >> 6;
    const int wm = (wave & 1) * 64;          // row half
    const int wn = (wave >> 1) * 128;        // col quarter
    const int rowBase = blockIdx.x * 128;
    const int bIdx = blockIdx.x >> 5;        // 32 blocks per batch

    f4_t acc[4][8];
#pragma unroll
    for (int i = 0; i < 4; i++)
#pragma unroll
        for (int j = 0; j < 8; j++) acc[i][j] = (f4_t)0.0f;

    // A staging: thread -> (row = tid>>3 [+64], kelem = (tid&7)*8), 8 elems x 2 halves
    const int ar = tid >> 3;
    const int ak = (tid & 7) * 8;
    const float* aSrc0 = value + (size_t)(rowBase + ar) * 1024 + ak;
    const float* aSrc1 = aSrc0 + (size_t)64 * 1024;
    const int aswz = ak ^ ((ar & 7) << 3);
    const int aOff0 = ar * 64 + aswz;
    const int aOff1 = (ar + 64) * 64 + aswz;

    // fragment addressing (row&7 == lane&7 for both A and B since wm,wn are mult of 8)
    const int sw = (lane & 7) << 3;
    const int ko = (lane >> 4) * 8;
    const int am = wm + (lane & 15);
    const int bn = wn + (lane & 15);

    float4 a0, a1, a2, a3;

    // ---- prologue: stage kt=0 ----
    a0 = *(const float4*)(aSrc0);
    a1 = *(const float4*)(aSrc0 + 4);
    a2 = *(const float4*)(aSrc1);
    a3 = *(const float4*)(aSrc1 + 4);
    {
        const unsigned short* gB = wvbf;
        unsigned short* lB = &Bs[0][0];
#pragma unroll
        for (int c = 0; c < 8; c++)
            gload16(gB + (c * 512 + tid) * 8, lB + (c * 512 + tid) * 8);
    }
    asm volatile("s_waitcnt vmcnt(8)" ::: "memory");   // A regs (issued before the 8 gloads)
    {
        uint4 p0, p1;
        p0.x = pk2(a0.x, a0.y); p0.y = pk2(a0.z, a0.w);
        p0.z = pk2(a1.x, a1.y); p0.w = pk2(a1.z, a1.w);
        p1.x = pk2(a2.x, a2.y); p1.y = pk2(a2.z, a2.w);
        p1.z = pk2(a3.x, a3.y); p1.w = pk2(a3.z, a3.w);
        *(uint4*)&As[aOff0] = p0;
        *(uint4*)&As[aOff1] = p1;
    }
    asm volatile("s_waitcnt vmcnt(0) lgkmcnt(0)" ::: "memory");
    __builtin_amdgcn_s_barrier();
    __builtin_amdgcn_sched_barrier(0);

    // ---- main loop ----
    for (int kt = 0; kt < 16; ++kt) {
        const int cur = kt & 1;
        if (kt < 15) {
            // issue next-step loads: A (4) first, then B (8) -> vmcnt(8) retires A only
            const float* s0 = aSrc0 + (kt + 1) * 64;
            const float* s1 = aSrc1 + (kt + 1) * 64;
            a0 = *(const float4*)(s0);
            a1 = *(const float4*)(s0 + 4);
            a2 = *(const float4*)(s1);
            a3 = *(const float4*)(s1 + 4);
            const unsigned short* gB = wvbf + (size_t)(kt + 1) * 32768;
            unsigned short* lB = &Bs[cur ^ 1][0];
#pragma unroll
            for (int c = 0; c < 8; c++)
                gload16(gB + (c * 512 + tid) * 8, lB + (c * 512 + tid) * 8);
        }
        // compute kt: 2 k-slices x (4 A-frags, 8 B-frags, 32 MFMAs)
        const unsigned short* Bp = &Bs[cur][0];
#pragma unroll
        for (int ks = 0; ks < 2; ++ks) {
            const int kq = (ks * 32 + ko) ^ sw;
            bf8_t af[4];
#pragma unroll
            for (int i = 0; i < 4; i++)
                af[i] = *(const bf8_t*)&As[(am + i * 16) * 64 + kq];
#pragma unroll
            for (int j = 0; j < 8; j++) {
                bf8_t bv = *(const bf8_t*)&Bp[(bn + j * 16) * 64 + kq];
#pragma unroll
                for (int i = 0; i < 4; i++)
                    acc[i][j] = __builtin_amdgcn_mfma_f32_16x16x32_bf16(af[i], bv, acc[i][j], 0, 0, 0);
            }
        }
        __builtin_amdgcn_s_barrier();            // all reads of As / Bs[cur] done
        if (kt < 15) {
            asm volatile("s_waitcnt vmcnt(8)" ::: "memory");   // A regs landed (hidden under MFMA)
            uint4 p0, p1;
            p0.x = pk2(a0.x, a0.y); p0.y = pk2(a0.z, a0.w);
            p0.z = pk2(a1.x, a1.y); p0.w = pk2(a1.z, a1.w);
            p1.x = pk2(a2.x, a2.y); p1.y = pk2(a2.z, a2.w);
            p1.z = pk2(a3.x, a3.y); p1.w = pk2(a3.z, a3.w);
            *(uint4*)&As[aOff0] = p0;
            *(uint4*)&As[aOff1] = p1;
            asm volatile("s_waitcnt vmcnt(0) lgkmcnt(0)" ::: "memory");  // B gloads + A writes done
        }
        __builtin_amdgcn_s_barrier();            // publish As(kt+1) + Bs[cur^1]
        __builtin_amdgcn_sched_barrier(0);
    }

    // ---- epilogue: conv taps + tanh + fc + sigmoid + bsum (unchanged, verified) ----
    if (tid < 128) {
        int grow = rowBase + tid;
        int t = grow & 4095;
        rowLa[0][tid] = (t == 0) ? 0.f : la[grow - 1];
        rowLa[1][tid] = la[grow];
        rowLa[2][tid] = (t == 4095) ? 0.f : la[grow + 1];
    }
    float qv[8], c0[8], c1[8], c2[8], fv[8];
#pragma unroll
    for (int j = 0; j < 8; j++) {
        int a = wn + j * 16 + (lane & 15);
        qv[j] = qb2[bIdx * 512 + a];
        c0[j] = a012[a]; c1[j] = a012[512 + a]; c2[j] = a012[1024 + a];
        fv[j] = fcw[a];
    }
    __syncthreads();

    const int q4 = lane >> 4;
#pragma unroll
    for (int i = 0; i < 4; i++) {
#pragma unroll
        for (int r = 0; r < 4; r++) {
            int row = wm + i * 16 + q4 * 4 + r;   // C/D: col=lane&15, row=(lane>>4)*4+reg
            float lm = rowLa[0][row], l0 = rowLa[1][row], lp = rowLa[2][row];
            float s = 0.f;
#pragma unroll
            for (int j = 0; j < 8; j++) {
                float x = acc[i][j][r] + qv[j] + lm * c0[j] + l0 * c1[j] + lp * c2[j];
                float e = __expf(2.f * x);
                s += fv[j] * (1.f - 2.f / (e + 1.f));   // tanh(x)*fc_w
            }
            s += __shfl_xor(s, 1); s += __shfl_xor(s, 2);
            s += __shfl_xor(s, 4); s += __shfl_xor(s, 8);
            if ((lane & 15) == 0) scoreRed[row][wave >> 1] = s;
        }
    }
    __syncthreads();

    if (tid < 128) {
        float full = scoreRed[tid][0] + scoreRed[tid][1] + scoreRed[tid][2] + scoreRed[tid][3];
        float sg = 1.f / (1.f + __expf(-full));
        sigbuf[rowBase + tid] = sg;
        float w = sg;
        w += __shfl_xor(w, 1); w += __shfl_xor(w, 2); w += __shfl_xor(w, 4);
        w += __shfl_xor(w, 8); w += __shfl_xor(w, 16); w += __shfl_xor(w, 32);
        if (lane == 0) atomicAdd(&bsum[bIdx], w);
    }
}

__global__ void k_align(const float* __restrict__ sig, const float* __restrict__ bsum,
                        float* __restrict__ out) {
    int i = blockIdx.x * 256 + threadIdx.x;
    out[i] = sig[i] / bsum[i >> 12];
}

// context: block = (t-chunk of 128, batch). 256 threads x float4 -> full contiguous
// 4 KB rows of value streamed sequentially (DRAM-friendly), atomic accumulate.
__global__ __launch_bounds__(256) void k_ctx(const float* __restrict__ value,
                                             const float* __restrict__ alignw,
                                             float* __restrict__ ctx) {
    int b = blockIdx.y;
    int t0 = blockIdx.x * 128;
    const float* vp = value + (size_t)(b * 4096 + t0) * 1024 + threadIdx.x * 4;
    const float* wp = alignw + b * 4096 + t0;
    float4 acc; acc.x = acc.y = acc.z = acc.w = 0.f;
#pragma unroll 4
    for (int t = 0; t < 128; ++t) {
        float w = wp[t];
        float4 v = *(const float4*)(vp + (size_t)t * 1024);
        acc.x += w * v.x; acc.y += w * v.y; acc.z += w * v.z; acc.w += w * v.w;
    }
    float* cp = ctx + b * 1024 + threadIdx.x * 4;
    atomicAdd(cp + 0, acc.x);
    atomicAdd(cp + 1, acc.y);
    atomicAdd(cp + 2, acc.z);
    atomicAdd(cp + 3, acc.w);
}

extern "C" void kernel_launch(void* const* d_in, const int* in_sizes, int n_in,
                              void* d_out, int out_size, void* d_ws, size_t ws_size,
                              hipStream_t stream) {
    const float* query = (const float*)d_in[0];
    const float* value = (const float*)d_in[1];
    const float* la    = (const float*)d_in[2];
    const float* convw = (const float*)d_in[3];
    const float* convb = (const float*)d_in[4];
    const float* WQ    = (const float*)d_in[5];
    const float* WV    = (const float*)d_in[6];
    const float* WU    = (const float*)d_in[7];
    const float* bias  = (const float*)d_in[8];
    const float* fcw   = (const float*)d_in[9];
    float* out = (float*)d_out;   // [context 32*1024 | align 32*4096]

    char* ws = (char*)d_ws;
    float* sigbuf = (float*)ws;                               // 131072 f
    float* qb2    = (float*)(ws + 524288);                    // 16384 f
    float* a012   = (float*)(ws + 589824);                    // 1536 f
    float* bsum   = (float*)(ws + 595968);                    // 32 f
    unsigned short* wvbf = (unsigned short*)(ws + 596096);    // 524288 bf16 (1 MB), tiled+swizzled

    hipMemsetAsync(bsum, 0, 32 * sizeof(float), stream);
    hipMemsetAsync(out, 0, 32 * 1024 * sizeof(float), stream);

    k_wv2bf<<<256, 256, 0, stream>>>(WV, wvbf);
    k_qb2<<<32, 256, 0, stream>>>(query, WQ, bias, convb, WU, qb2);
    k_a012<<<2, 256, 0, stream>>>(convw, WU, a012);
    k_gemm<<<1024, 512, 0, stream>>>(value, wvbf, qb2, a012, fcw, la, sigbuf, bsum);
    k_align<<<512, 256, 0, stream>>>(sigbuf, bsum, out + 32768);
    k_ctx<<<dim3(32, 32), 256, 0, stream>>>(value, out + 32768, out);
}